// Round 7
// baseline (133.153 us; speedup 1.0000x reference)
//
#include <hip/hip_runtime.h>

// Problem constants (from reference)
#define NSTARS 2048
#define BATCH  256
#define PF     28
#define NGE    512
#define GF     32
#define OPD2   65536   // 256*256
#define KTOT   (PF + GF)  // 60
#define TM     8       // batches per block (acc = 16 VGPR -> 8 waves/SIMD)
#define DEPTH  4       // register pipeline depth (60 % 4 == 0)
#define NGRP   (KTOT / DEPTH)  // 15 groups of 4 k-slices

typedef float f32x2 __attribute__((ext_vector_type(2)));

// ---------------------------------------------------------------------------
// Kernel 1: index search + W = [interm_poly | interm_graph] (k-major layout)
// Wt[k*BATCH + b], k in [0,60)
// ---------------------------------------------------------------------------
__global__ __launch_bounds__(256) void prep_kernel(
    const float* __restrict__ positions,  const float* __restrict__ obs_pos,
    const float* __restrict__ poly_dic,   const float* __restrict__ graph_dic,
    const float* __restrict__ alpha_poly, const float* __restrict__ alpha_graph,
    float* __restrict__ Wt)
{
    const int b = blockIdx.x;   // batch row
    const int t = threadIdx.x;  // 256 threads

    const float p0 = positions[2 * b];
    const float p1 = positions[2 * b + 1];

    // Faithful to argmax(eq.reshape(B,-1))//2 : first star n (row-major over
    // (n, coord)) where EITHER coordinate matches; all-false -> 0.
    int cand = 0x7fffffff;
    #pragma unroll
    for (int i = 0; i < NSTARS / 256; ++i) {
        const int n = t + i * 256;
        const float o0 = obs_pos[2 * n];
        const float o1 = obs_pos[2 * n + 1];
        if (o0 == p0 || o1 == p1) cand = min(cand, n);
    }
    __shared__ int smin[256];
    smin[t] = cand;
    __syncthreads();
    for (int s = 128; s > 0; s >>= 1) {
        if (t < s) smin[t] = min(smin[t], smin[t + s]);
        __syncthreads();
    }
    int idx = smin[0];
    if (idx == 0x7fffffff) idx = 0;  // argmax of all-False returns 0

    // interm_poly[j] = sum_p poly_dic[idx,p] * alpha_poly[p,j]
    if (t < PF) {
        float acc = 0.f;
        #pragma unroll
        for (int p = 0; p < PF; ++p)
            acc += poly_dic[idx * PF + p] * alpha_poly[p * PF + t];
        Wt[t * BATCH + b] = acc;
    }

    // interm_graph[g] = sum_e graph_dic[idx,e] * alpha_graph[e,g]
    // 8 partials of 64 elements each, reduced in LDS.
    __shared__ float psum[8][GF];
    {
        const int g = t & 31;
        const int r = t >> 5;
        float acc = 0.f;
        const int e0 = r * (NGE / 8);
        for (int e = e0; e < e0 + NGE / 8; ++e)
            acc += graph_dic[idx * NGE + e] * alpha_graph[e * GF + g];
        psum[r][g] = acc;
    }
    __syncthreads();
    if (t < GF) {
        float acc = 0.f;
        #pragma unroll
        for (int r = 0; r < 8; ++r) acc += psum[r][t];
        Wt[(PF + t) * BATCH + b] = acc;
    }
}

// ---------------------------------------------------------------------------
// Kernel 2: out[b, ij] = sum_k Wt[k, b] * S[k, ij]
// TM=8 batches x 512 ij (float2/thread) per block, 4096 blocks.
//
// Design (R0-R6 ledger: seven ILP/staging schedules all ~36-45 us; VALUBusy
// measured = exactly the 12.8 us FMA issue floor -> pure latency binding):
//  - MAX TLP: VGPR <= 64 enforced by __launch_bounds__(256, 8) -> 8 blocks/CU
//    co-resident = 32 waves/CU = 8 waves/SIMD (hardware max). At 8 waves/SIMD
//    each ~400cy load latency is covered by 8x64cy of other-wave FMA issue --
//    the hardware hides what 6 rounds of software pipelining could not.
//  - 16 blocks/CU of work at 8 resident = 2 generations: gen-1's stores
//    overlap gen-2's compute (no LDS throttle needed; zero LDS used).
//  - XCD swizzle: 16 x-slices per XCD -> 1.92 MB L2-resident S set, shared
//    by both generations (mapping depends only on id&7 and slot&15).
//  - W reads stay on the scalar path (block-uniform -> s_load, lgkm domain).
//  - Nontemporal stores: write-once output, don't evict S from L2.
// ---------------------------------------------------------------------------
__global__ __launch_bounds__(256, 8) void main_kernel(
    const float* __restrict__ S_poly, const float* __restrict__ S_graph,
    const float* __restrict__ Wt, float* __restrict__ out)
{
    const int t    = threadIdx.x;
    const int id   = blockIdx.x;             // 0..4095
    const int xcd  = id & 7;
    const int slot = id >> 3;                // 0..511
    const int xb   = xcd * 16 + (slot & 15); // 0..127 (16 x-slices per XCD)
    const int yb   = slot >> 4;              // 0..31
    const int ij   = xb * 512 + t * 2;
    const int b0   = yb * TM;

    const float* __restrict__ wp = Wt + b0;  // block-uniform -> s_load

    f32x2 acc[TM];
    #pragma unroll
    for (int b = 0; b < TM; ++b) acc[b] = (f32x2)(0.f);

    // This thread's float2 in S slice k (uniform scalar poly/graph select).
    auto srow = [&](int k) -> const f32x2* {
        const float* base = (k < PF) ? (S_poly  + (size_t)k * OPD2)
                                     : (S_graph + (size_t)(k - PF) * OPD2);
        return reinterpret_cast<const f32x2*>(base + ij);
    };

    // one k-step: issue reload (k+DEPTH) early, then FMA with the old value
    auto kstep = [&](int k, f32x2& sv, bool reload) {
        const f32x2 s = sv;
        if (reload) sv = *srow(k + DEPTH);
        const float* wk = wp + k * BATCH;   // uniform -> s_load_dwordx8
        #pragma unroll
        for (int b = 0; b < TM; ++b)
            acc[b] += wk[b] * s;
    };

    // prologue: fill the 4-deep pipeline
    f32x2 sv0 = *srow(0), sv1 = *srow(1), sv2 = *srow(2), sv3 = *srow(3);

    #pragma unroll 1
    for (int T = 0; T < NGRP - 1; ++T) {
        const int kg = T * DEPTH;
        kstep(kg + 0, sv0, true);
        kstep(kg + 1, sv1, true);
        kstep(kg + 2, sv2, true);
        kstep(kg + 3, sv3, true);
    }
    {   // last group: drain, no reload
        const int kg = (NGRP - 1) * DEPTH;
        kstep(kg + 0, sv0, false);
        kstep(kg + 1, sv1, false);
        kstep(kg + 2, sv2, false);
        kstep(kg + 3, sv3, false);
    }

    #pragma unroll
    for (int b = 0; b < TM; ++b) {
        __builtin_nontemporal_store(
            acc[b],
            reinterpret_cast<f32x2*>(out + (size_t)(b0 + b) * OPD2 + ij));
    }
}

// ---------------------------------------------------------------------------
extern "C" void kernel_launch(void* const* d_in, const int* in_sizes, int n_in,
                              void* d_out, int out_size, void* d_ws, size_t ws_size,
                              hipStream_t stream) {
    const float* positions   = (const float*)d_in[0];  // (256, 2)
    const float* obs_pos     = (const float*)d_in[1];  // (2048, 2)
    const float* poly_dic    = (const float*)d_in[2];  // (2048, 28)
    const float* graph_dic   = (const float*)d_in[3];  // (2048, 512)
    const float* alpha_poly  = (const float*)d_in[4];  // (28, 28)
    const float* alpha_graph = (const float*)d_in[5];  // (512, 32)
    const float* S_poly      = (const float*)d_in[6];  // (28, 256, 256)
    const float* S_graph     = (const float*)d_in[7];  // (32, 256, 256)
    float* out = (float*)d_out;                        // (256, 256, 256)

    float* Wt = (float*)d_ws;  // KTOT * BATCH floats = 60 KB

    prep_kernel<<<BATCH, 256, 0, stream>>>(positions, obs_pos, poly_dic,
                                           graph_dic, alpha_poly, alpha_graph,
                                           Wt);

    main_kernel<<<4096, 256, 0, stream>>>(S_poly, S_graph, Wt, out);
}

// Round 8
// 131.389 us; speedup vs baseline: 1.0134x; 1.0134x over previous
//
#include <hip/hip_runtime.h>

// Problem constants (from reference)
#define NSTARS 2048
#define BATCH  256
#define PF     28
#define NGE    512
#define GF     32
#define OPD2   65536   // 256*256
#define KTOT   (PF + GF)  // 60
#define TM     16      // batches per block (f32x2 acc = 32 VGPR)
#define DEPTH  4       // register pipeline depth (60 % 4 == 0)
#define NGRP   (KTOT / DEPTH)  // 15 groups of 4 k-slices

typedef float f32x2 __attribute__((ext_vector_type(2)));

// ---------------------------------------------------------------------------
// Kernel 1: index search + W = [interm_poly | interm_graph] (k-major layout)
// Wt[k*BATCH + b], k in [0,60)
// ---------------------------------------------------------------------------
__global__ __launch_bounds__(256) void prep_kernel(
    const float* __restrict__ positions,  const float* __restrict__ obs_pos,
    const float* __restrict__ poly_dic,   const float* __restrict__ graph_dic,
    const float* __restrict__ alpha_poly, const float* __restrict__ alpha_graph,
    float* __restrict__ Wt)
{
    const int b = blockIdx.x;   // batch row
    const int t = threadIdx.x;  // 256 threads

    const float p0 = positions[2 * b];
    const float p1 = positions[2 * b + 1];

    // Faithful to argmax(eq.reshape(B,-1))//2 : first star n (row-major over
    // (n, coord)) where EITHER coordinate matches; all-false -> 0.
    int cand = 0x7fffffff;
    #pragma unroll
    for (int i = 0; i < NSTARS / 256; ++i) {
        const int n = t + i * 256;
        const float o0 = obs_pos[2 * n];
        const float o1 = obs_pos[2 * n + 1];
        if (o0 == p0 || o1 == p1) cand = min(cand, n);
    }
    __shared__ int smin[256];
    smin[t] = cand;
    __syncthreads();
    for (int s = 128; s > 0; s >>= 1) {
        if (t < s) smin[t] = min(smin[t], smin[t + s]);
        __syncthreads();
    }
    int idx = smin[0];
    if (idx == 0x7fffffff) idx = 0;  // argmax of all-False returns 0

    // interm_poly[j] = sum_p poly_dic[idx,p] * alpha_poly[p,j]
    if (t < PF) {
        float acc = 0.f;
        #pragma unroll
        for (int p = 0; p < PF; ++p)
            acc += poly_dic[idx * PF + p] * alpha_poly[p * PF + t];
        Wt[t * BATCH + b] = acc;
    }

    // interm_graph[g] = sum_e graph_dic[idx,e] * alpha_graph[e,g]
    // 8 partials of 64 elements each, reduced in LDS.
    __shared__ float psum[8][GF];
    {
        const int g = t & 31;
        const int r = t >> 5;
        float acc = 0.f;
        const int e0 = r * (NGE / 8);
        for (int e = e0; e < e0 + NGE / 8; ++e)
            acc += graph_dic[idx * NGE + e] * alpha_graph[e * GF + g];
        psum[r][g] = acc;
    }
    __syncthreads();
    if (t < GF) {
        float acc = 0.f;
        #pragma unroll
        for (int r = 0; r < 8; ++r) acc += psum[r][t];
        Wt[(PF + t) * BATCH + b] = acc;
    }
}

// ---------------------------------------------------------------------------
// Kernel 2: out[b, ij] = sum_k Wt[k, b] * S[k, ij]
// TM=16 batches x 512 ij (f32x2/thread) per block, 2048 blocks.
//
// R0-R7 ledger conclusion: two regimes observed --
//   high-reuse/low-waves (TM=16+, <=16 waves/CU): latency-bound, 6.6 TB/s
//     read rate (far under ceiling), main ~38-45 us;
//   low-reuse/high-waves (TM=8, 20-32 waves/CU): read-BW-bound, 503 MB of
//     L2/L3 reads at 11.7-14.4 TB/s, main ~35-43 us.
// This config takes the unexplored cell: HIGH reuse AND HIGH occupancy.
//   - f32x2 accumulators: acc = 16x2 = 32 VGPR, total ~55 -> 8 blocks/CU
//     co-resident = 32 waves/CU (hardware max TLP for latency hiding).
//   - TM=16 -> S replication 16x = 251 MB cache reads (half of R6/R7) ->
//     ~18 us at the demonstrated ~14 TB/s, overlapped with the ~14.5 us
//     VALU issue floor.
//   - XCD swizzle: 16 x-slices/XCD = 1.92 MB L2-resident S set.
//   - W on the scalar path (block-uniform -> s_load, lgkm domain).
//   - Nontemporal stores (write-once output).
// ---------------------------------------------------------------------------
__global__ __launch_bounds__(256, 8) void main_kernel(
    const float* __restrict__ S_poly, const float* __restrict__ S_graph,
    const float* __restrict__ Wt, float* __restrict__ out)
{
    const int t    = threadIdx.x;
    const int id   = blockIdx.x;             // 0..2047
    const int xcd  = id & 7;
    const int slot = id >> 3;                // 0..255
    const int xb   = xcd * 16 + (slot & 15); // 0..127 (16 x-slices per XCD)
    const int yb   = slot >> 4;              // 0..15
    const int ij   = xb * 512 + t * 2;
    const int b0   = yb * TM;

    const float* __restrict__ wp = Wt + b0;  // block-uniform -> s_load

    f32x2 acc[TM];
    #pragma unroll
    for (int b = 0; b < TM; ++b) acc[b] = (f32x2)(0.f);

    // This thread's float2 in S slice k (uniform scalar poly/graph select).
    auto srow = [&](int k) -> const f32x2* {
        const float* base = (k < PF) ? (S_poly  + (size_t)k * OPD2)
                                     : (S_graph + (size_t)(k - PF) * OPD2);
        return reinterpret_cast<const f32x2*>(base + ij);
    };

    // one k-step: issue reload (k+DEPTH) early, then FMA with the old value
    auto kstep = [&](int k, f32x2& sv, bool reload) {
        const f32x2 s = sv;
        if (reload) sv = *srow(k + DEPTH);
        const float* wk = wp + k * BATCH;   // uniform -> s_load
        #pragma unroll
        for (int b = 0; b < TM; ++b)
            acc[b] += wk[b] * s;
    };

    // prologue: fill the 4-deep pipeline
    f32x2 sv0 = *srow(0), sv1 = *srow(1), sv2 = *srow(2), sv3 = *srow(3);

    #pragma unroll 1
    for (int T = 0; T < NGRP - 1; ++T) {
        const int kg = T * DEPTH;
        kstep(kg + 0, sv0, true);
        kstep(kg + 1, sv1, true);
        kstep(kg + 2, sv2, true);
        kstep(kg + 3, sv3, true);
    }
    {   // last group: drain, no reload
        const int kg = (NGRP - 1) * DEPTH;
        kstep(kg + 0, sv0, false);
        kstep(kg + 1, sv1, false);
        kstep(kg + 2, sv2, false);
        kstep(kg + 3, sv3, false);
    }

    #pragma unroll
    for (int b = 0; b < TM; ++b) {
        __builtin_nontemporal_store(
            acc[b],
            reinterpret_cast<f32x2*>(out + (size_t)(b0 + b) * OPD2 + ij));
    }
}

// ---------------------------------------------------------------------------
extern "C" void kernel_launch(void* const* d_in, const int* in_sizes, int n_in,
                              void* d_out, int out_size, void* d_ws, size_t ws_size,
                              hipStream_t stream) {
    const float* positions   = (const float*)d_in[0];  // (256, 2)
    const float* obs_pos     = (const float*)d_in[1];  // (2048, 2)
    const float* poly_dic    = (const float*)d_in[2];  // (2048, 28)
    const float* graph_dic   = (const float*)d_in[3];  // (2048, 512)
    const float* alpha_poly  = (const float*)d_in[4];  // (28, 28)
    const float* alpha_graph = (const float*)d_in[5];  // (512, 32)
    const float* S_poly      = (const float*)d_in[6];  // (28, 256, 256)
    const float* S_graph     = (const float*)d_in[7];  // (32, 256, 256)
    float* out = (float*)d_out;                        // (256, 256, 256)

    float* Wt = (float*)d_ws;  // KTOT * BATCH floats = 60 KB

    prep_kernel<<<BATCH, 256, 0, stream>>>(positions, obs_pos, poly_dic,
                                           graph_dic, alpha_poly, alpha_graph,
                                           Wt);

    main_kernel<<<2048, 256, 0, stream>>>(S_poly, S_graph, Wt, out);
}